// Round 15
// baseline (451.775 us; speedup 1.0000x reference)
//
#include <hip/hip_runtime.h>
#include <hip/hip_bf16.h>

#define NNODES 50000
#define NEDGES 800000
#define ETOT   850000
#define NEG_SLOPE 0.2f
#define LN_EPS 1e-5f
#define SM_EPS 1e-16f
#define NSLICE 16
#define RANGE_SZ ((NNODES + 7) / 8)   // 6250

typedef short bf16x8 __attribute__((ext_vector_type(8)));
typedef float f32x4  __attribute__((ext_vector_type(4)));
typedef float v2f    __attribute__((ext_vector_type(2)));

__device__ __forceinline__ unsigned pack_bf2(float a, float b) {
    __hip_bfloat162 p;
    p.x = __float2bfloat16(a);
    p.y = __float2bfloat16(b);
    return *reinterpret_cast<unsigned*>(&p);
}

__device__ __forceinline__ v2f bf2_to_f2(unsigned u) {
    v2f r;
    r.x = __int_as_float((int)(u << 16));
    r.y = __int_as_float((int)(u & 0xFFFF0000u));
    return r;
}

template <int CTRL>
__device__ __forceinline__ float dpp_add(float x) {
    return x + __int_as_float(__builtin_amdgcn_update_dpp(
        0, __float_as_int(x), CTRL, 0xF, 0xF, true));
}
__device__ __forceinline__ float red16(float x) {
    x = dpp_add<0xB1>(x);
    x = dpp_add<0x4E>(x);
    x = dpp_add<0x124>(x);
    x = dpp_add<0x128>(x);
    return x;
}

__device__ __forceinline__ float edot2(v2f x01, v2f x23, v2f xr01, v2f xr23,
                                       v2f a01, v2f a23) {
    v2f s01 = x01 + xr01;
    v2f s23 = x23 + xr23;
    v2f t01 = __builtin_elementwise_max(s01, s01 * NEG_SLOPE);
    v2f t23 = __builtin_elementwise_max(s23, s23 * NEG_SLOPE);
    v2f d = t01 * a01 + t23 * a23;
    return d.x + d.y;
}

// XOR-swizzled LDS offset for 64-col short tiles (16B granules)
__device__ __forceinline__ int sw(int row, int c8) {
    return (row << 6) + ((c8 ^ (row & 7)) << 3);
}

// ---------------- pure streaming prep: cast x + weights + csr pad ----------------
// Round-14 lesson: device-scope atomics dirty HBM lines regardless of XCD affinity
// (WRITE 52MB unchanged) -> all global atomics removed from the pipeline.
__global__ void k_cast_all(const float* __restrict__ X, __hip_bfloat16* __restrict__ XB,
                           const float* __restrict__ W1l, const float* __restrict__ W1r,
                           const float* __restrict__ W2l, const float* __restrict__ W2r,
                           __hip_bfloat16* __restrict__ w1lT, __hip_bfloat16* __restrict__ w1rT,
                           __hip_bfloat16* __restrict__ w2lT, __hip_bfloat16* __restrict__ w2rT,
                           unsigned short* __restrict__ csr_src) {
    int tid = blockIdx.x * 256 + threadIdx.x;
    if (tid < 16) csr_src[ETOT + tid] = 0;   // pad: node-0 reads, weight-masked
    if (tid < 1600000) {                     // x: 12.8M elems, 8 per thread
        float4 a = reinterpret_cast<const float4*>(X)[2 * tid];
        float4 b = reinterpret_cast<const float4*>(X)[2 * tid + 1];
        uint4 o;
        o.x = pack_bf2(a.x, a.y);
        o.y = pack_bf2(a.z, a.w);
        o.z = pack_bf2(b.x, b.y);
        o.w = pack_bf2(b.z, b.w);
        reinterpret_cast<uint4*>(XB)[tid] = o;
    } else {
        int t = tid - 1600000;
        if (t < 65536) {
            int k = t >> 8, n = t & 255;
            w1lT[n * 256 + k] = __float2bfloat16(W1l[t]);
        } else if (t < 131072) {
            int u = t - 65536; int k = u >> 8, n = u & 255;
            w1rT[n * 256 + k] = __float2bfloat16(W1r[u]);
        } else if (t < 135168) {
            int u = t - 131072; int k = u >> 6, n = u & 63;
            w2lT[n * 64 + k] = __float2bfloat16(W2l[u]);
        } else if (t < 139264) {
            int u = t - 135168; int k = u >> 6, n = u & 63;
            w2rT[n * 64 + k] = __float2bfloat16(W2r[u]);
        }
    }
}

// ---------------- per-slice LDS histogram (no global atomics) ----------------
// block b: dst range b&7, edge slice b>>3. part[s][i] = #edges in slice s with dst i.
__global__ void __launch_bounds__(256) k_hist_part(const int* __restrict__ ei,
                                                   int* __restrict__ part) {
    __shared__ int cnt[RANGE_SZ];
    const int r = blockIdx.x & 7;
    const int s = blockIdx.x >> 3;
    const int lo = r * RANGE_SZ;
    const int hi = (lo + RANGE_SZ < NNODES) ? lo + RANGE_SZ : NNODES;
    for (int k = threadIdx.x; k < RANGE_SZ; k += 256) cnt[k] = 0;
    __syncthreads();
    const int C = (ETOT + NSLICE - 1) / NSLICE;
    const int e0 = s * C;
    const int e1 = (e0 + C < ETOT) ? e0 + C : ETOT;
    for (int e = e0 + threadIdx.x; e < e1; e += 256) {
        int dst = (e < NEDGES) ? ei[NEDGES + e] : (e - NEDGES);
        if (dst >= lo && dst < hi) atomicAdd(&cnt[dst - lo], 1);
    }
    __syncthreads();
    for (int k = threadIdx.x; k + lo < hi; k += 256)
        part[s * NNODES + lo + k] = cnt[k];
}

// ---------------- CSR scan (deg = sum of 16 slice partials) ----------------
__global__ void k_scan1(const int* __restrict__ part, int* __restrict__ rowstart,
                        int* __restrict__ blocksum) {
    __shared__ int s[256];
    int t = threadIdx.x;
    int i = blockIdx.x * 256 + t;
    int v = 0;
    if (i < NNODES) {
        #pragma unroll
        for (int sl = 0; sl < NSLICE; ++sl) v += part[sl * NNODES + i];
    }
    s[t] = v;
    __syncthreads();
    #pragma unroll
    for (int off = 1; off < 256; off <<= 1) {
        int add = (t >= off) ? s[t - off] : 0;
        __syncthreads();
        s[t] += add;
        __syncthreads();
    }
    if (i < NNODES) rowstart[i] = s[t] - v;
    if (t == 255) blocksum[blockIdx.x] = s[255];
}

__global__ void k_scan2(int* __restrict__ bs, int nb) {
    __shared__ int s[256];
    int t = threadIdx.x;
    int v = (t < nb) ? bs[t] : 0;
    s[t] = v;
    __syncthreads();
    #pragma unroll
    for (int off = 1; off < 256; off <<= 1) {
        int add = (t >= off) ? s[t - off] : 0;
        __syncthreads();
        s[t] += add;
        __syncthreads();
    }
    if (t < nb) bs[t] = s[t] - v;
}

__global__ void k_scan3(int* __restrict__ rowstart, const int* __restrict__ boff) {
    int i = blockIdx.x * 256 + threadIdx.x;
    if (i < NNODES) {
        rowstart[i] += boff[i >> 8];
    } else if (i == NNODES) {
        rowstart[NNODES] = ETOT;
    }
}

// per-slice write offsets: offs[s][i] = rowstart[i] + sum_{s'<s} part[s'][i]
__global__ void k_offs(const int* __restrict__ rowstart, const int* __restrict__ part,
                       int* __restrict__ offs) {
    int i = blockIdx.x * 256 + threadIdx.x;
    if (i >= NNODES) return;
    int off = rowstart[i];
    #pragma unroll
    for (int s = 0; s < NSLICE; ++s) {
        offs[s * NNODES + i] = off;
        off += part[s * NNODES + i];
    }
}

// ---------------- scatter with LDS cursor (no global atomics) ----------------
__global__ void __launch_bounds__(256) k_scatter(const int* __restrict__ ei,
                                                 const int* __restrict__ offs,
                                                 unsigned short* __restrict__ csr_src) {
    __shared__ int cur[RANGE_SZ];
    const int r = blockIdx.x & 7;
    const int s = blockIdx.x >> 3;
    const int lo = r * RANGE_SZ;
    const int hi = (lo + RANGE_SZ < NNODES) ? lo + RANGE_SZ : NNODES;
    for (int k = threadIdx.x; k + lo < hi; k += 256)
        cur[k] = offs[s * NNODES + lo + k];
    __syncthreads();
    const int C = (ETOT + NSLICE - 1) / NSLICE;
    const int e0 = s * C;
    const int e1 = (e0 + C < ETOT) ? e0 + C : ETOT;
    for (int e = e0 + threadIdx.x; e < e1; e += 256) {
        int dst = (e < NEDGES) ? ei[NEDGES + e] : (e - NEDGES);
        if (dst >= lo && dst < hi) {
            int src = (e < NEDGES) ? ei[e] : dst;
            int pos = atomicAdd(&cur[dst - lo], 1);   // LDS atomic
            csr_src[pos] = (unsigned short)src;
        }
    }
}

// ---------------- dual-output MFMA bf16 GEMM, 64x64 tile, swizzled LDS (24 KB) ----
template <int KDIM, int NC>
__global__ __launch_bounds__(256) void k_gemm_dual(
    const __hip_bfloat16* __restrict__ A,
    const __hip_bfloat16* __restrict__ WTl,
    const __hip_bfloat16* __restrict__ WTr,
    __hip_bfloat16* __restrict__ Cl,
    __hip_bfloat16* __restrict__ Cr, int M)
{
    __shared__ short As[64 * 64];
    __shared__ short Bls[64 * 64];
    __shared__ short Brs[64 * 64];
    const int t = threadIdx.x;
    const int m0 = blockIdx.x * 64;
    const int n0 = blockIdx.y * 64;
    const int wave = t >> 6, lane = t & 63;
    const int wm = wave & 1, wn = wave >> 1;
    const int l15 = lane & 15, quad = lane >> 4;

    f32x4 accl[2][2] = {};
    f32x4 accr[2][2] = {};
    for (int k0 = 0; k0 < KDIM; k0 += 64) {
        __syncthreads();
        #pragma unroll
        for (int it = 0; it < 2; ++it) {
            int f = t + 256 * it;
            int r = f >> 3, c8 = f & 7;
            int row = m0 + r;
            uint4 v = make_uint4(0u, 0u, 0u, 0u);
            if (row < M) v = *reinterpret_cast<const uint4*>(&A[(size_t)row * KDIM + k0 + c8 * 8]);
            *reinterpret_cast<uint4*>(&As[sw(r, c8)]) = v;
        }
        #pragma unroll
        for (int it = 0; it < 2; ++it) {
            int f = t + 256 * it;
            int n = f >> 3, c8 = f & 7;
            *reinterpret_cast<uint4*>(&Bls[sw(n, c8)]) =
                *reinterpret_cast<const uint4*>(&WTl[(size_t)(n0 + n) * KDIM + k0 + c8 * 8]);
            *reinterpret_cast<uint4*>(&Brs[sw(n, c8)]) =
                *reinterpret_cast<const uint4*>(&WTr[(size_t)(n0 + n) * KDIM + k0 + c8 * 8]);
        }
        __syncthreads();
        #pragma unroll
        for (int kk8 = 0; kk8 < 8; kk8 += 4) {
            bf16x8 af[2], bl[2], br[2];
            #pragma unroll
            for (int mi = 0; mi < 2; ++mi)
                af[mi] = *reinterpret_cast<const bf16x8*>(
                    &As[sw(wm * 32 + mi * 16 + l15, kk8 + quad)]);
            #pragma unroll
            for (int ni = 0; ni < 2; ++ni) {
                int rB = wn * 32 + ni * 16 + l15;
                bl[ni] = *reinterpret_cast<const bf16x8*>(&Bls[sw(rB, kk8 + quad)]);
                br[ni] = *reinterpret_cast<const bf16x8*>(&Brs[sw(rB, kk8 + quad)]);
            }
            #pragma unroll
            for (int mi = 0; mi < 2; ++mi)
                #pragma unroll
                for (int ni = 0; ni < 2; ++ni) {
                    accl[mi][ni] = __builtin_amdgcn_mfma_f32_16x16x32_bf16(
                        af[mi], bl[ni], accl[mi][ni], 0, 0, 0);
                    accr[mi][ni] = __builtin_amdgcn_mfma_f32_16x16x32_bf16(
                        af[mi], br[ni], accr[mi][ni], 0, 0, 0);
                }
        }
    }
    #pragma unroll
    for (int mi = 0; mi < 2; ++mi)
        #pragma unroll
        for (int ni = 0; ni < 2; ++ni)
            #pragma unroll
            for (int r = 0; r < 4; ++r) {
                int row = m0 + wm * 32 + mi * 16 + quad * 4 + r;
                int col = n0 + wn * 32 + ni * 16 + l15;
                if (row < M) {
                    Cl[(size_t)row * NC + col] = __float2bfloat16(accl[mi][ni][r]);
                    Cr[(size_t)row * NC + col] = __float2bfloat16(accr[mi][ni][r]);
                }
            }
}

// ---------------- layer 1: one node per 64-thread workgroup ----
__global__ void __launch_bounds__(64) k_node1(
                        const __hip_bfloat16* __restrict__ xl,
                        const __hip_bfloat16* __restrict__ xr,
                        const int* __restrict__ rowstart,
                        const unsigned short* __restrict__ csr_src,
                        const float* __restrict__ att,   // [4,64]
                        const float* __restrict__ bias,  // [64]
                        const float* __restrict__ lng,
                        const float* __restrict__ lnb,
                        __hip_bfloat16* __restrict__ h1b, int base) {
    const int i = base + blockIdx.x;
    const int lane = threadIdx.x;
    const int grp = lane >> 4;
    const int c0 = (lane & 15) * 4;
    const int fb = lane * 4;

    uint2 rraw = *reinterpret_cast<const uint2*>(xr + (size_t)i * 256 + fb);
    v2f xr01 = bf2_to_f2(rraw.x), xr23 = bf2_to_f2(rraw.y);
    const float4 av = *reinterpret_cast<const float4*>(att + fb);
    v2f a01 = {av.x, av.y}, a23 = {av.z, av.w};

    v2f Lab = {0.f, 0.f}, Lcd = {0.f, 0.f};
    v2f Aa01 = {0.f, 0.f}, Aa23 = {0.f, 0.f};
    v2f Ab01 = {0.f, 0.f}, Ab23 = {0.f, 0.f};

    const int p0 = rowstart[i], p1 = rowstart[i + 1];
    for (int p = p0; p < p1; p += 4) {
        int j0 = csr_src[p];
        int j1 = csr_src[p + 1];   // pad-safe
        int j2 = csr_src[p + 2];
        int j3 = csr_src[p + 3];
        uint2 g0 = *reinterpret_cast<const uint2*>(xl + (size_t)j0 * 256 + fb);
        uint2 g1 = *reinterpret_cast<const uint2*>(xl + (size_t)j1 * 256 + fb);
        uint2 g2 = *reinterpret_cast<const uint2*>(xl + (size_t)j2 * 256 + fb);
        uint2 g3 = *reinterpret_cast<const uint2*>(xl + (size_t)j3 * 256 + fb);
        v2f x001 = bf2_to_f2(g0.x), x023 = bf2_to_f2(g0.y);
        v2f x101 = bf2_to_f2(g1.x), x123 = bf2_to_f2(g1.y);
        v2f x201 = bf2_to_f2(g2.x), x223 = bf2_to_f2(g2.y);
        v2f x301 = bf2_to_f2(g3.x), x323 = bf2_to_f2(g3.y);
        float e0 = red16(edot2(x001, x023, xr01, xr23, a01, a23));
        float e1 = red16(edot2(x101, x123, xr01, xr23, a01, a23));
        float e2 = red16(edot2(x201, x223, xr01, xr23, a01, a23));
        float e3 = red16(edot2(x301, x323, xr01, xr23, a01, a23));
        float pe0 = __expf(fminf(e0, 60.f));
        float pe1 = (p + 1 < p1) ? __expf(fminf(e1, 60.f)) : 0.f;
        float pe2 = (p + 2 < p1) ? __expf(fminf(e2, 60.f)) : 0.f;
        float pe3 = (p + 3 < p1) ? __expf(fminf(e3, 60.f)) : 0.f;
        Lab += (v2f){pe0, pe1};
        Lcd += (v2f){pe2, pe3};
        Aa01 += x001 * pe0; Aa23 += x023 * pe0;
        Ab01 += x101 * pe1; Ab23 += x123 * pe1;
        Aa01 += x201 * pe2; Aa23 += x223 * pe2;
        Ab01 += x301 * pe3; Ab23 += x323 * pe3;
    }
    float l = (Lab.x + Lab.y) + (Lcd.x + Lcd.y);
    float inv = 1.f / (l + SM_EPS);
    v2f V01 = (Aa01 + Ab01) * inv;
    v2f V23 = (Aa23 + Ab23) * inv;
    float v0 = V01.x, v1 = V01.y, v2 = V23.x, v3 = V23.y;
    v0 += __shfl_xor(v0, 16); v0 += __shfl_xor(v0, 32);
    v1 += __shfl_xor(v1, 16); v1 += __shfl_xor(v1, 32);
    v2 += __shfl_xor(v2, 16); v2 += __shfl_xor(v2, 32);
    v3 += __shfl_xor(v3, 16); v3 += __shfl_xor(v3, 32);
    const float4 bv = *reinterpret_cast<const float4*>(bias + c0);
    float o0 = v0 * 0.25f + bv.x;
    float o1 = v1 * 0.25f + bv.y;
    float o2 = v2 * 0.25f + bv.z;
    float o3 = v3 * 0.25f + bv.w;
    float mu = red16(o0 + o1 + o2 + o3) * 0.015625f;
    float d0 = o0 - mu, d1 = o1 - mu, d2 = o2 - mu, d3 = o3 - mu;
    float ss = red16(d0 * d0 + d1 * d1 + d2 * d2 + d3 * d3);
    float istd = rsqrtf(ss * 0.015625f + LN_EPS);
    const float4 gv = *reinterpret_cast<const float4*>(lng + c0);
    const float4 bb = *reinterpret_cast<const float4*>(lnb + c0);
    float h0 = fmaxf(d0 * istd * gv.x + bb.x, 0.f);
    float h1 = fmaxf(d1 * istd * gv.y + bb.y, 0.f);
    float h2 = fmaxf(d2 * istd * gv.z + bb.z, 0.f);
    float h3 = fmaxf(d3 * istd * gv.w + bb.w, 0.f);
    if (grp == 0) {
        uint2 pk;
        pk.x = pack_bf2(h0, h1);
        pk.y = pack_bf2(h2, h3);
        *reinterpret_cast<uint2*>(h1b + (size_t)i * 64 + c0) = pk;
    }
}

// ---------------- layer 2: one node per 64-thread workgroup, final LN ----
__global__ void __launch_bounds__(64) k_node2(
                        const __hip_bfloat16* __restrict__ xl,
                        const __hip_bfloat16* __restrict__ xr,
                        const int* __restrict__ rowstart,
                        const unsigned short* __restrict__ csr_src,
                        const float* __restrict__ att,   // [64]
                        const float* __restrict__ bias,
                        const float* __restrict__ lng,
                        const float* __restrict__ lnb,
                        float* __restrict__ out) {
    const int i = blockIdx.x;
    const int lane = threadIdx.x;
    const int grp = lane >> 4;
    const int c0 = (lane & 15) * 4;

    uint2 rraw = *reinterpret_cast<const uint2*>(xr + (size_t)i * 64 + c0);
    v2f xr01 = bf2_to_f2(rraw.x), xr23 = bf2_to_f2(rraw.y);
    const float4 avf = *reinterpret_cast<const float4*>(att + c0);
    v2f a01 = {avf.x, avf.y}, a23 = {avf.z, avf.w};
    float l = 0.f;
    v2f A01 = {0.f, 0.f}, A23 = {0.f, 0.f};

    const char* rowbase = (const char*)xl + c0 * 2;
    const int p0 = rowstart[i], p1 = rowstart[i + 1];
    for (int p = p0; p < p1; p += 4) {
        int pe = p + grp;
        int j = csr_src[pe];                          // pad-safe
        uint2 g = *reinterpret_cast<const uint2*>(rowbase + ((size_t)j << 7));
        v2f x01 = bf2_to_f2(g.x), x23 = bf2_to_f2(g.y);
        float e = red16(edot2(x01, x23, xr01, xr23, a01, a23));
        float w = (pe < p1) ? __expf(fminf(e, 60.f)) : 0.f;
        l += w;
        A01 += x01 * w;
        A23 += x23 * w;
    }
    #pragma unroll
    for (int s = 16; s <= 32; s <<= 1) {
        l     += __shfl_xor(l, s);
        A01.x += __shfl_xor(A01.x, s);
        A01.y += __shfl_xor(A01.y, s);
        A23.x += __shfl_xor(A23.x, s);
        A23.y += __shfl_xor(A23.y, s);
    }
    float inv = 1.f / (l + SM_EPS);
    const float4 bv = *reinterpret_cast<const float4*>(bias + c0);
    float o0 = A01.x * inv + bv.x;
    float o1 = A01.y * inv + bv.y;
    float o2 = A23.x * inv + bv.z;
    float o3 = A23.y * inv + bv.w;
    float mu = red16(o0 + o1 + o2 + o3) * 0.015625f;
    float d0 = o0 - mu, d1 = o1 - mu, d2 = o2 - mu, d3 = o3 - mu;
    float ss = red16(d0 * d0 + d1 * d1 + d2 * d2 + d3 * d3);
    float istd = rsqrtf(ss * 0.015625f + LN_EPS);
    const float4 gv = *reinterpret_cast<const float4*>(lng + c0);
    const float4 bb = *reinterpret_cast<const float4*>(lnb + c0);
    if (grp == 0) {
        float4 y;
        y.x = d0 * istd * gv.x + bb.x;
        y.y = d1 * istd * gv.y + bb.y;
        y.z = d2 * istd * gv.z + bb.z;
        y.w = d3 * istd * gv.w + bb.w;
        *reinterpret_cast<float4*>(out + (size_t)i * 64 + c0) = y;
    }
}

extern "C" void kernel_launch(void* const* d_in, const int* in_sizes, int n_in,
                              void* d_out, int out_size, void* d_ws, size_t ws_size,
                              hipStream_t stream) {
    const float* x    = (const float*)d_in[0];
    const int*   ei   = (const int*)d_in[1];
    const float* W1l  = (const float*)d_in[2];
    const float* W1r  = (const float*)d_in[3];
    const float* att1 = (const float*)d_in[4];
    const float* b1   = (const float*)d_in[5];
    const float* ln1g = (const float*)d_in[6];
    const float* ln1b = (const float*)d_in[7];
    const float* W2l  = (const float*)d_in[8];
    const float* W2r  = (const float*)d_in[9];
    const float* att2 = (const float*)d_in[10];
    const float* b2   = (const float*)d_in[11];
    const float* ln2g = (const float*)d_in[12];
    const float* ln2b = (const float*)d_in[13];
    float* out = (float*)d_out;

    char* w = (char*)d_ws;
    size_t off = 0;
    auto alloc = [&](size_t bytes) -> void* {
        void* p = w + off;
        off += (bytes + 255) & ~(size_t)255;
        return p;
    };
    __hip_bfloat16* xb   = (__hip_bfloat16*)alloc((size_t)NNODES * 256 * 2);
    __hip_bfloat16* xl1  = (__hip_bfloat16*)alloc((size_t)NNODES * 256 * 2);
    __hip_bfloat16* xr1  = (__hip_bfloat16*)alloc((size_t)NNODES * 256 * 2);
    __hip_bfloat16* h1b  = (__hip_bfloat16*)alloc((size_t)NNODES * 64 * 2);
    __hip_bfloat16* xl2  = (__hip_bfloat16*)alloc((size_t)NNODES * 64 * 2);
    __hip_bfloat16* xr2  = (__hip_bfloat16*)alloc((size_t)NNODES * 64 * 2);
    __hip_bfloat16* w1lT = (__hip_bfloat16*)alloc(256 * 256 * 2);
    __hip_bfloat16* w1rT = (__hip_bfloat16*)alloc(256 * 256 * 2);
    __hip_bfloat16* w2lT = (__hip_bfloat16*)alloc(64 * 64 * 2);
    __hip_bfloat16* w2rT = (__hip_bfloat16*)alloc(64 * 64 * 2);
    int* part     = (int*)alloc((size_t)NSLICE * NNODES * 4);
    int* offs     = (int*)alloc((size_t)NSLICE * NNODES * 4);
    int* rowstart = (int*)alloc((size_t)(NNODES + 1) * 4);
    unsigned short* csr_src = (unsigned short*)alloc((size_t)(ETOT + 16) * 2);
    int* blocksum = (int*)alloc(1024);
    (void)ws_size; (void)in_sizes; (void)n_in; (void)out_size;

    k_cast_all<<<6794, 256, 0, stream>>>(x, xb, W1l, W1r, W2l, W2r,
                                         w1lT, w1rT, w2lT, w2rT, csr_src);
    k_hist_part<<<8 * NSLICE, 256, 0, stream>>>(ei, part);

    const int scanB = (NNODES + 255) / 256;
    k_scan1<<<scanB, 256, 0, stream>>>(part, rowstart, blocksum);
    k_scan2<<<1, 256, 0, stream>>>(blocksum, scanB);
    k_scan3<<<scanB, 256, 0, stream>>>(rowstart, blocksum);
    k_offs<<<scanB, 256, 0, stream>>>(rowstart, part, offs);
    k_scatter<<<8 * NSLICE, 256, 0, stream>>>(ei, offs, csr_src);

    dim3 gm1((NNODES + 63) / 64, 4);
    k_gemm_dual<256, 256><<<gm1, 256, 0, stream>>>(xb, w1lT, w1rT, xl1, xr1, NNODES);
    k_node1<<<NNODES / 2, 64, 0, stream>>>(xl1, xr1, rowstart, csr_src,
                                           att1, b1, ln1g, ln1b, h1b, 0);
    k_node1<<<NNODES / 2, 64, 0, stream>>>(xl1, xr1, rowstart, csr_src,
                                           att1, b1, ln1g, ln1b, h1b, NNODES / 2);
    dim3 gm2((NNODES + 63) / 64, 1);
    k_gemm_dual<64, 64><<<gm2, 256, 0, stream>>>(h1b, w2lT, w2rT, xl2, xr2, NNODES);
    k_node2<<<NNODES, 64, 0, stream>>>(xl2, xr2, rowstart, csr_src,
                                       att2, b2, ln2g, ln2b, out);
}

// Round 16
// 329.471 us; speedup vs baseline: 1.3712x; 1.3712x over previous
//
#include <hip/hip_runtime.h>
#include <hip/hip_bf16.h>

#define NNODES 50000
#define NEDGES 800000
#define ETOT   850000
#define NEG_SLOPE 0.2f
#define LN_EPS 1e-5f
#define SM_EPS 1e-16f
#define NSLICE 64
#define RANGE_SZ ((NNODES + 7) / 8)   // 6250

typedef short bf16x8 __attribute__((ext_vector_type(8)));
typedef float f32x4  __attribute__((ext_vector_type(4)));
typedef float v2f    __attribute__((ext_vector_type(2)));

__device__ __forceinline__ unsigned pack_bf2(float a, float b) {
    __hip_bfloat162 p;
    p.x = __float2bfloat16(a);
    p.y = __float2bfloat16(b);
    return *reinterpret_cast<unsigned*>(&p);
}

__device__ __forceinline__ v2f bf2_to_f2(unsigned u) {
    v2f r;
    r.x = __int_as_float((int)(u << 16));
    r.y = __int_as_float((int)(u & 0xFFFF0000u));
    return r;
}

template <int CTRL>
__device__ __forceinline__ float dpp_add(float x) {
    return x + __int_as_float(__builtin_amdgcn_update_dpp(
        0, __float_as_int(x), CTRL, 0xF, 0xF, true));
}
__device__ __forceinline__ float red16(float x) {
    x = dpp_add<0xB1>(x);
    x = dpp_add<0x4E>(x);
    x = dpp_add<0x124>(x);
    x = dpp_add<0x128>(x);
    return x;
}

__device__ __forceinline__ float edot2(v2f x01, v2f x23, v2f xr01, v2f xr23,
                                       v2f a01, v2f a23) {
    v2f s01 = x01 + xr01;
    v2f s23 = x23 + xr23;
    v2f t01 = __builtin_elementwise_max(s01, s01 * NEG_SLOPE);
    v2f t23 = __builtin_elementwise_max(s23, s23 * NEG_SLOPE);
    v2f d = t01 * a01 + t23 * a23;
    return d.x + d.y;
}

// XOR-swizzled LDS offset for 64-col short tiles (16B granules)
__device__ __forceinline__ int sw(int row, int c8) {
    return (row << 6) + ((c8 ^ (row & 7)) << 3);
}

// ---------------- pure streaming prep: cast x + weights + csr pad ----------------
__global__ void k_cast_all(const float* __restrict__ X, __hip_bfloat16* __restrict__ XB,
                           const float* __restrict__ W1l, const float* __restrict__ W1r,
                           const float* __restrict__ W2l, const float* __restrict__ W2r,
                           __hip_bfloat16* __restrict__ w1lT, __hip_bfloat16* __restrict__ w1rT,
                           __hip_bfloat16* __restrict__ w2lT, __hip_bfloat16* __restrict__ w2rT,
                           unsigned short* __restrict__ csr_src) {
    int tid = blockIdx.x * 256 + threadIdx.x;
    if (tid < 16) csr_src[ETOT + tid] = 0;   // pad: node-0 reads, weight-masked
    if (tid < 1600000) {                     // x: 12.8M elems, 8 per thread
        float4 a = reinterpret_cast<const float4*>(X)[2 * tid];
        float4 b = reinterpret_cast<const float4*>(X)[2 * tid + 1];
        uint4 o;
        o.x = pack_bf2(a.x, a.y);
        o.y = pack_bf2(a.z, a.w);
        o.z = pack_bf2(b.x, b.y);
        o.w = pack_bf2(b.z, b.w);
        reinterpret_cast<uint4*>(XB)[tid] = o;
    } else {
        int t = tid - 1600000;
        if (t < 65536) {
            int k = t >> 8, n = t & 255;
            w1lT[n * 256 + k] = __float2bfloat16(W1l[t]);
        } else if (t < 131072) {
            int u = t - 65536; int k = u >> 8, n = u & 255;
            w1rT[n * 256 + k] = __float2bfloat16(W1r[u]);
        } else if (t < 135168) {
            int u = t - 131072; int k = u >> 6, n = u & 63;
            w2lT[n * 64 + k] = __float2bfloat16(W2l[u]);
        } else if (t < 139264) {
            int u = t - 135168; int k = u >> 6, n = u & 63;
            w2rT[n * 64 + k] = __float2bfloat16(W2r[u]);
        }
    }
}

// ---------------- per-slice LDS histogram (no global atomics) ----------------
// block b: dst range b&7, edge slice b>>3. 512 blocks (round-15 lesson: 128 was
// grid-starved -> 5% occupancy, 138 µs).
__global__ void __launch_bounds__(256) k_hist_part(const int* __restrict__ ei,
                                                   int* __restrict__ part) {
    __shared__ int cnt[RANGE_SZ];
    const int r = blockIdx.x & 7;
    const int s = blockIdx.x >> 3;
    const int lo = r * RANGE_SZ;
    const int hi = (lo + RANGE_SZ < NNODES) ? lo + RANGE_SZ : NNODES;
    for (int k = threadIdx.x; k < RANGE_SZ; k += 256) cnt[k] = 0;
    __syncthreads();
    const int C = (ETOT + NSLICE - 1) / NSLICE;
    const int e0 = s * C;
    const int e1 = (e0 + C < ETOT) ? e0 + C : ETOT;
    for (int e = e0 + threadIdx.x; e < e1; e += 256) {
        int dst = (e < NEDGES) ? ei[NEDGES + e] : (e - NEDGES);
        if (dst >= lo && dst < hi) atomicAdd(&cnt[dst - lo], 1);
    }
    __syncthreads();
    for (int k = threadIdx.x; k + lo < hi; k += 256)
        part[s * NNODES + lo + k] = cnt[k];
}

// ---------------- CSR scan (deg = sum of slice partials) ----------------
__global__ void k_scan1(const int* __restrict__ part, int* __restrict__ rowstart,
                        int* __restrict__ blocksum) {
    __shared__ int s[256];
    int t = threadIdx.x;
    int i = blockIdx.x * 256 + t;
    int v = 0;
    if (i < NNODES) {
        #pragma unroll 8
        for (int sl = 0; sl < NSLICE; ++sl) v += part[sl * NNODES + i];
    }
    s[t] = v;
    __syncthreads();
    #pragma unroll
    for (int off = 1; off < 256; off <<= 1) {
        int add = (t >= off) ? s[t - off] : 0;
        __syncthreads();
        s[t] += add;
        __syncthreads();
    }
    if (i < NNODES) rowstart[i] = s[t] - v;
    if (t == 255) blocksum[blockIdx.x] = s[255];
}

__global__ void k_scan2(int* __restrict__ bs, int nb) {
    __shared__ int s[256];
    int t = threadIdx.x;
    int v = (t < nb) ? bs[t] : 0;
    s[t] = v;
    __syncthreads();
    #pragma unroll
    for (int off = 1; off < 256; off <<= 1) {
        int add = (t >= off) ? s[t - off] : 0;
        __syncthreads();
        s[t] += add;
        __syncthreads();
    }
    if (t < nb) bs[t] = s[t] - v;
}

__global__ void k_scan3(int* __restrict__ rowstart, const int* __restrict__ boff) {
    int i = blockIdx.x * 256 + threadIdx.x;
    if (i < NNODES) {
        rowstart[i] += boff[i >> 8];
    } else if (i == NNODES) {
        rowstart[NNODES] = ETOT;
    }
}

// per-slice write offsets: offs[s][i] = rowstart[i] + sum_{s'<s} part[s'][i]
__global__ void k_offs(const int* __restrict__ rowstart, const int* __restrict__ part,
                       int* __restrict__ offs) {
    int i = blockIdx.x * 256 + threadIdx.x;
    if (i >= NNODES) return;
    int off = rowstart[i];
    #pragma unroll 8
    for (int s = 0; s < NSLICE; ++s) {
        offs[s * NNODES + i] = off;
        off += part[s * NNODES + i];
    }
}

// ---------------- scatter with LDS cursor (no global atomics) ----------------
__global__ void __launch_bounds__(256) k_scatter(const int* __restrict__ ei,
                                                 const int* __restrict__ offs,
                                                 unsigned short* __restrict__ csr_src) {
    __shared__ int cur[RANGE_SZ];
    const int r = blockIdx.x & 7;
    const int s = blockIdx.x >> 3;
    const int lo = r * RANGE_SZ;
    const int hi = (lo + RANGE_SZ < NNODES) ? lo + RANGE_SZ : NNODES;
    for (int k = threadIdx.x; k + lo < hi; k += 256)
        cur[k] = offs[s * NNODES + lo + k];
    __syncthreads();
    const int C = (ETOT + NSLICE - 1) / NSLICE;
    const int e0 = s * C;
    const int e1 = (e0 + C < ETOT) ? e0 + C : ETOT;
    for (int e = e0 + threadIdx.x; e < e1; e += 256) {
        int dst = (e < NEDGES) ? ei[NEDGES + e] : (e - NEDGES);
        if (dst >= lo && dst < hi) {
            int src = (e < NEDGES) ? ei[e] : dst;
            int pos = atomicAdd(&cur[dst - lo], 1);   // LDS atomic
            csr_src[pos] = (unsigned short)src;
        }
    }
}

// ---------------- dual-output MFMA bf16 GEMM, 64x64 tile, swizzled LDS (24 KB) ----
template <int KDIM, int NC>
__global__ __launch_bounds__(256) void k_gemm_dual(
    const __hip_bfloat16* __restrict__ A,
    const __hip_bfloat16* __restrict__ WTl,
    const __hip_bfloat16* __restrict__ WTr,
    __hip_bfloat16* __restrict__ Cl,
    __hip_bfloat16* __restrict__ Cr, int M)
{
    __shared__ short As[64 * 64];
    __shared__ short Bls[64 * 64];
    __shared__ short Brs[64 * 64];
    const int t = threadIdx.x;
    const int m0 = blockIdx.x * 64;
    const int n0 = blockIdx.y * 64;
    const int wave = t >> 6, lane = t & 63;
    const int wm = wave & 1, wn = wave >> 1;
    const int l15 = lane & 15, quad = lane >> 4;

    f32x4 accl[2][2] = {};
    f32x4 accr[2][2] = {};
    for (int k0 = 0; k0 < KDIM; k0 += 64) {
        __syncthreads();
        #pragma unroll
        for (int it = 0; it < 2; ++it) {
            int f = t + 256 * it;
            int r = f >> 3, c8 = f & 7;
            int row = m0 + r;
            uint4 v = make_uint4(0u, 0u, 0u, 0u);
            if (row < M) v = *reinterpret_cast<const uint4*>(&A[(size_t)row * KDIM + k0 + c8 * 8]);
            *reinterpret_cast<uint4*>(&As[sw(r, c8)]) = v;
        }
        #pragma unroll
        for (int it = 0; it < 2; ++it) {
            int f = t + 256 * it;
            int n = f >> 3, c8 = f & 7;
            *reinterpret_cast<uint4*>(&Bls[sw(n, c8)]) =
                *reinterpret_cast<const uint4*>(&WTl[(size_t)(n0 + n) * KDIM + k0 + c8 * 8]);
            *reinterpret_cast<uint4*>(&Brs[sw(n, c8)]) =
                *reinterpret_cast<const uint4*>(&WTr[(size_t)(n0 + n) * KDIM + k0 + c8 * 8]);
        }
        __syncthreads();
        #pragma unroll
        for (int kk8 = 0; kk8 < 8; kk8 += 4) {
            bf16x8 af[2], bl[2], br[2];
            #pragma unroll
            for (int mi = 0; mi < 2; ++mi)
                af[mi] = *reinterpret_cast<const bf16x8*>(
                    &As[sw(wm * 32 + mi * 16 + l15, kk8 + quad)]);
            #pragma unroll
            for (int ni = 0; ni < 2; ++ni) {
                int rB = wn * 32 + ni * 16 + l15;
                bl[ni] = *reinterpret_cast<const bf16x8*>(&Bls[sw(rB, kk8 + quad)]);
                br[ni] = *reinterpret_cast<const bf16x8*>(&Brs[sw(rB, kk8 + quad)]);
            }
            #pragma unroll
            for (int mi = 0; mi < 2; ++mi)
                #pragma unroll
                for (int ni = 0; ni < 2; ++ni) {
                    accl[mi][ni] = __builtin_amdgcn_mfma_f32_16x16x32_bf16(
                        af[mi], bl[ni], accl[mi][ni], 0, 0, 0);
                    accr[mi][ni] = __builtin_amdgcn_mfma_f32_16x16x32_bf16(
                        af[mi], br[ni], accr[mi][ni], 0, 0, 0);
                }
        }
    }
    #pragma unroll
    for (int mi = 0; mi < 2; ++mi)
        #pragma unroll
        for (int ni = 0; ni < 2; ++ni)
            #pragma unroll
            for (int r = 0; r < 4; ++r) {
                int row = m0 + wm * 32 + mi * 16 + quad * 4 + r;
                int col = n0 + wn * 32 + ni * 16 + l15;
                if (row < M) {
                    Cl[(size_t)row * NC + col] = __float2bfloat16(accl[mi][ni][r]);
                    Cr[(size_t)row * NC + col] = __float2bfloat16(accr[mi][ni][r]);
                }
            }
}

// ---------------- layer 1: one node per 64-thread workgroup ----
__global__ void __launch_bounds__(64) k_node1(
                        const __hip_bfloat16* __restrict__ xl,
                        const __hip_bfloat16* __restrict__ xr,
                        const int* __restrict__ rowstart,
                        const unsigned short* __restrict__ csr_src,
                        const float* __restrict__ att,   // [4,64]
                        const float* __restrict__ bias,  // [64]
                        const float* __restrict__ lng,
                        const float* __restrict__ lnb,
                        __hip_bfloat16* __restrict__ h1b, int base) {
    const int i = base + blockIdx.x;
    const int lane = threadIdx.x;
    const int grp = lane >> 4;
    const int c0 = (lane & 15) * 4;
    const int fb = lane * 4;

    uint2 rraw = *reinterpret_cast<const uint2*>(xr + (size_t)i * 256 + fb);
    v2f xr01 = bf2_to_f2(rraw.x), xr23 = bf2_to_f2(rraw.y);
    const float4 av = *reinterpret_cast<const float4*>(att + fb);
    v2f a01 = {av.x, av.y}, a23 = {av.z, av.w};

    v2f Lab = {0.f, 0.f}, Lcd = {0.f, 0.f};
    v2f Aa01 = {0.f, 0.f}, Aa23 = {0.f, 0.f};
    v2f Ab01 = {0.f, 0.f}, Ab23 = {0.f, 0.f};

    const int p0 = rowstart[i], p1 = rowstart[i + 1];
    for (int p = p0; p < p1; p += 4) {
        int j0 = csr_src[p];
        int j1 = csr_src[p + 1];   // pad-safe
        int j2 = csr_src[p + 2];
        int j3 = csr_src[p + 3];
        uint2 g0 = *reinterpret_cast<const uint2*>(xl + (size_t)j0 * 256 + fb);
        uint2 g1 = *reinterpret_cast<const uint2*>(xl + (size_t)j1 * 256 + fb);
        uint2 g2 = *reinterpret_cast<const uint2*>(xl + (size_t)j2 * 256 + fb);
        uint2 g3 = *reinterpret_cast<const uint2*>(xl + (size_t)j3 * 256 + fb);
        v2f x001 = bf2_to_f2(g0.x), x023 = bf2_to_f2(g0.y);
        v2f x101 = bf2_to_f2(g1.x), x123 = bf2_to_f2(g1.y);
        v2f x201 = bf2_to_f2(g2.x), x223 = bf2_to_f2(g2.y);
        v2f x301 = bf2_to_f2(g3.x), x323 = bf2_to_f2(g3.y);
        float e0 = red16(edot2(x001, x023, xr01, xr23, a01, a23));
        float e1 = red16(edot2(x101, x123, xr01, xr23, a01, a23));
        float e2 = red16(edot2(x201, x223, xr01, xr23, a01, a23));
        float e3 = red16(edot2(x301, x323, xr01, xr23, a01, a23));
        float pe0 = __expf(fminf(e0, 60.f));
        float pe1 = (p + 1 < p1) ? __expf(fminf(e1, 60.f)) : 0.f;
        float pe2 = (p + 2 < p1) ? __expf(fminf(e2, 60.f)) : 0.f;
        float pe3 = (p + 3 < p1) ? __expf(fminf(e3, 60.f)) : 0.f;
        Lab += (v2f){pe0, pe1};
        Lcd += (v2f){pe2, pe3};
        Aa01 += x001 * pe0; Aa23 += x023 * pe0;
        Ab01 += x101 * pe1; Ab23 += x123 * pe1;
        Aa01 += x201 * pe2; Aa23 += x223 * pe2;
        Ab01 += x301 * pe3; Ab23 += x323 * pe3;
    }
    float l = (Lab.x + Lab.y) + (Lcd.x + Lcd.y);
    float inv = 1.f / (l + SM_EPS);
    v2f V01 = (Aa01 + Ab01) * inv;
    v2f V23 = (Aa23 + Ab23) * inv;
    float v0 = V01.x, v1 = V01.y, v2 = V23.x, v3 = V23.y;
    v0 += __shfl_xor(v0, 16); v0 += __shfl_xor(v0, 32);
    v1 += __shfl_xor(v1, 16); v1 += __shfl_xor(v1, 32);
    v2 += __shfl_xor(v2, 16); v2 += __shfl_xor(v2, 32);
    v3 += __shfl_xor(v3, 16); v3 += __shfl_xor(v3, 32);
    const float4 bv = *reinterpret_cast<const float4*>(bias + c0);
    float o0 = v0 * 0.25f + bv.x;
    float o1 = v1 * 0.25f + bv.y;
    float o2 = v2 * 0.25f + bv.z;
    float o3 = v3 * 0.25f + bv.w;
    float mu = red16(o0 + o1 + o2 + o3) * 0.015625f;
    float d0 = o0 - mu, d1 = o1 - mu, d2 = o2 - mu, d3 = o3 - mu;
    float ss = red16(d0 * d0 + d1 * d1 + d2 * d2 + d3 * d3);
    float istd = rsqrtf(ss * 0.015625f + LN_EPS);
    const float4 gv = *reinterpret_cast<const float4*>(lng + c0);
    const float4 bb = *reinterpret_cast<const float4*>(lnb + c0);
    float h0 = fmaxf(d0 * istd * gv.x + bb.x, 0.f);
    float h1 = fmaxf(d1 * istd * gv.y + bb.y, 0.f);
    float h2 = fmaxf(d2 * istd * gv.z + bb.z, 0.f);
    float h3 = fmaxf(d3 * istd * gv.w + bb.w, 0.f);
    if (grp == 0) {
        uint2 pk;
        pk.x = pack_bf2(h0, h1);
        pk.y = pack_bf2(h2, h3);
        *reinterpret_cast<uint2*>(h1b + (size_t)i * 64 + c0) = pk;
    }
}

// ---------------- layer 2: one node per 64-thread workgroup, final LN ----
__global__ void __launch_bounds__(64) k_node2(
                        const __hip_bfloat16* __restrict__ xl,
                        const __hip_bfloat16* __restrict__ xr,
                        const int* __restrict__ rowstart,
                        const unsigned short* __restrict__ csr_src,
                        const float* __restrict__ att,   // [64]
                        const float* __restrict__ bias,
                        const float* __restrict__ lng,
                        const float* __restrict__ lnb,
                        float* __restrict__ out) {
    const int i = blockIdx.x;
    const int lane = threadIdx.x;
    const int grp = lane >> 4;
    const int c0 = (lane & 15) * 4;

    uint2 rraw = *reinterpret_cast<const uint2*>(xr + (size_t)i * 64 + c0);
    v2f xr01 = bf2_to_f2(rraw.x), xr23 = bf2_to_f2(rraw.y);
    const float4 avf = *reinterpret_cast<const float4*>(att + c0);
    v2f a01 = {avf.x, avf.y}, a23 = {avf.z, avf.w};
    float l = 0.f;
    v2f A01 = {0.f, 0.f}, A23 = {0.f, 0.f};

    const char* rowbase = (const char*)xl + c0 * 2;
    const int p0 = rowstart[i], p1 = rowstart[i + 1];
    for (int p = p0; p < p1; p += 4) {
        int pe = p + grp;
        int j = csr_src[pe];                          // pad-safe
        uint2 g = *reinterpret_cast<const uint2*>(rowbase + ((size_t)j << 7));
        v2f x01 = bf2_to_f2(g.x), x23 = bf2_to_f2(g.y);
        float e = red16(edot2(x01, x23, xr01, xr23, a01, a23));
        float w = (pe < p1) ? __expf(fminf(e, 60.f)) : 0.f;
        l += w;
        A01 += x01 * w;
        A23 += x23 * w;
    }
    #pragma unroll
    for (int s = 16; s <= 32; s <<= 1) {
        l     += __shfl_xor(l, s);
        A01.x += __shfl_xor(A01.x, s);
        A01.y += __shfl_xor(A01.y, s);
        A23.x += __shfl_xor(A23.x, s);
        A23.y += __shfl_xor(A23.y, s);
    }
    float inv = 1.f / (l + SM_EPS);
    const float4 bv = *reinterpret_cast<const float4*>(bias + c0);
    float o0 = A01.x * inv + bv.x;
    float o1 = A01.y * inv + bv.y;
    float o2 = A23.x * inv + bv.z;
    float o3 = A23.y * inv + bv.w;
    float mu = red16(o0 + o1 + o2 + o3) * 0.015625f;
    float d0 = o0 - mu, d1 = o1 - mu, d2 = o2 - mu, d3 = o3 - mu;
    float ss = red16(d0 * d0 + d1 * d1 + d2 * d2 + d3 * d3);
    float istd = rsqrtf(ss * 0.015625f + LN_EPS);
    const float4 gv = *reinterpret_cast<const float4*>(lng + c0);
    const float4 bb = *reinterpret_cast<const float4*>(lnb + c0);
    if (grp == 0) {
        float4 y;
        y.x = d0 * istd * gv.x + bb.x;
        y.y = d1 * istd * gv.y + bb.y;
        y.z = d2 * istd * gv.z + bb.z;
        y.w = d3 * istd * gv.w + bb.w;
        *reinterpret_cast<float4*>(out + (size_t)i * 64 + c0) = y;
    }
}

extern "C" void kernel_launch(void* const* d_in, const int* in_sizes, int n_in,
                              void* d_out, int out_size, void* d_ws, size_t ws_size,
                              hipStream_t stream) {
    const float* x    = (const float*)d_in[0];
    const int*   ei   = (const int*)d_in[1];
    const float* W1l  = (const float*)d_in[2];
    const float* W1r  = (const float*)d_in[3];
    const float* att1 = (const float*)d_in[4];
    const float* b1   = (const float*)d_in[5];
    const float* ln1g = (const float*)d_in[6];
    const float* ln1b = (const float*)d_in[7];
    const float* W2l  = (const float*)d_in[8];
    const float* W2r  = (const float*)d_in[9];
    const float* att2 = (const float*)d_in[10];
    const float* b2   = (const float*)d_in[11];
    const float* ln2g = (const float*)d_in[12];
    const float* ln2b = (const float*)d_in[13];
    float* out = (float*)d_out;

    char* w = (char*)d_ws;
    size_t off = 0;
    auto alloc = [&](size_t bytes) -> void* {
        void* p = w + off;
        off += (bytes + 255) & ~(size_t)255;
        return p;
    };
    __hip_bfloat16* xb   = (__hip_bfloat16*)alloc((size_t)NNODES * 256 * 2);
    __hip_bfloat16* xl1  = (__hip_bfloat16*)alloc((size_t)NNODES * 256 * 2);
    __hip_bfloat16* xr1  = (__hip_bfloat16*)alloc((size_t)NNODES * 256 * 2);
    __hip_bfloat16* h1b  = (__hip_bfloat16*)alloc((size_t)NNODES * 64 * 2);
    __hip_bfloat16* xl2  = (__hip_bfloat16*)alloc((size_t)NNODES * 64 * 2);
    __hip_bfloat16* xr2  = (__hip_bfloat16*)alloc((size_t)NNODES * 64 * 2);
    __hip_bfloat16* w1lT = (__hip_bfloat16*)alloc(256 * 256 * 2);
    __hip_bfloat16* w1rT = (__hip_bfloat16*)alloc(256 * 256 * 2);
    __hip_bfloat16* w2lT = (__hip_bfloat16*)alloc(64 * 64 * 2);
    __hip_bfloat16* w2rT = (__hip_bfloat16*)alloc(64 * 64 * 2);
    int* part     = (int*)alloc((size_t)NSLICE * NNODES * 4);
    int* offs     = (int*)alloc((size_t)NSLICE * NNODES * 4);
    int* rowstart = (int*)alloc((size_t)(NNODES + 1) * 4);
    unsigned short* csr_src = (unsigned short*)alloc((size_t)(ETOT + 16) * 2);
    int* blocksum = (int*)alloc(1024);
    (void)ws_size; (void)in_sizes; (void)n_in; (void)out_size;

    k_cast_all<<<6794, 256, 0, stream>>>(x, xb, W1l, W1r, W2l, W2r,
                                         w1lT, w1rT, w2lT, w2rT, csr_src);
    k_hist_part<<<8 * NSLICE, 256, 0, stream>>>(ei, part);

    const int scanB = (NNODES + 255) / 256;
    k_scan1<<<scanB, 256, 0, stream>>>(part, rowstart, blocksum);
    k_scan2<<<1, 256, 0, stream>>>(blocksum, scanB);
    k_scan3<<<scanB, 256, 0, stream>>>(rowstart, blocksum);
    k_offs<<<scanB, 256, 0, stream>>>(rowstart, part, offs);
    k_scatter<<<8 * NSLICE, 256, 0, stream>>>(ei, offs, csr_src);

    dim3 gm1((NNODES + 63) / 64, 4);
    k_gemm_dual<256, 256><<<gm1, 256, 0, stream>>>(xb, w1lT, w1rT, xl1, xr1, NNODES);
    k_node1<<<NNODES / 2, 64, 0, stream>>>(xl1, xr1, rowstart, csr_src,
                                           att1, b1, ln1g, ln1b, h1b, 0);
    k_node1<<<NNODES / 2, 64, 0, stream>>>(xl1, xr1, rowstart, csr_src,
                                           att1, b1, ln1g, ln1b, h1b, NNODES / 2);
    dim3 gm2((NNODES + 63) / 64, 1);
    k_gemm_dual<64, 64><<<gm2, 256, 0, stream>>>(h1b, w2lT, w2rT, xl2, xr2, NNODES);
    k_node2<<<NNODES, 64, 0, stream>>>(xl2, xr2, rowstart, csr_src,
                                       att2, b2, ln2g, ln2b, out);
}